// Round 7
// baseline (365.105 us; speedup 1.0000x reference)
//
#include <hip/hip_runtime.h>
#include <hip/hip_bf16.h>
#include <math.h>

#define H 128
#define H2 256
#define SLAB 96    // slots per row; P(Poisson(32) > 96) ~ 1e-18

typedef __attribute__((ext_vector_type(8))) short s16x8;
typedef __attribute__((ext_vector_type(4))) float f32x4;

__device__ __forceinline__ unsigned short f2bf(float f) {
  unsigned u = __float_as_uint(f);
  unsigned r = (u + 0x7FFFu + ((u >> 16) & 1u)) >> 16;
  return (unsigned short)r;
}
__device__ __forceinline__ float bf2f(unsigned short s) {
  return __uint_as_float(((unsigned)s) << 16);
}

// ---------------------------------------------------------------------------
// Weight prep: transpose to [n][k] + bf16 (split hi/lo for Wq, Wk).
// ---------------------------------------------------------------------------
__global__ void wprep(const float* __restrict__ Wq, const float* __restrict__ Wk,
                      const float* __restrict__ Wv, const float* __restrict__ W1,
                      const float* __restrict__ W2,
                      short* qh, short* ql, short* kh, short* kl,
                      short* vh, short* w1h, short* w2h)
{
  int job = blockIdx.z;
  const float* src; short* dh; short* dl = nullptr; int Kd, Nn;
  if (job == 0)      { src = Wq; dh = qh;  dl = ql; Kd = 128; Nn = 128; }
  else if (job == 1) { src = Wk; dh = kh;  dl = kl; Kd = 128; Nn = 128; }
  else if (job == 2) { src = Wv; dh = vh;           Kd = 128; Nn = 128; }
  else if (job == 3) { src = W1; dh = w1h;          Kd = 128; Nn = 256; }
  else               { src = W2; dh = w2h;          Kd = 256; Nn = 128; }
  int t = blockIdx.x * 256 + threadIdx.x;
  if (t >= Kd * Nn) return;
  int n = t / Kd, k = t - n * Kd;
  float v = src[(size_t)k * Nn + n];
  unsigned short h = f2bf(v);
  dh[t] = (short)h;
  if (dl) dl[t] = (short)f2bf(v - bf2f(h));
}

// ---------------------------------------------------------------------------
// QKV: LDS-free, barrier-free MFMA. 16-row tiles (grid N/16 = 1024),
// 4 waves x 32 cols. A (x rows) split-bf16 in registers; B fragments
// gathered from L2-hot transposed weights. Q,K split; V single (x-hi only).
// ---------------------------------------------------------------------------
__global__ __launch_bounds__(256) void qkv_mfma(
    const float* __restrict__ x,
    const short* __restrict__ Wqh, const short* __restrict__ Wql,
    const short* __restrict__ Wkh, const short* __restrict__ Wkl,
    const short* __restrict__ Wvh,
    const float* __restrict__ bq, const float* __restrict__ bk,
    const float* __restrict__ bv,
    float* __restrict__ Q, float* __restrict__ Km,
    unsigned short* __restrict__ Vbf)
{
  int tid = threadIdx.x;
  int wave = tid >> 6, lane = tid & 63;
  int quad = lane >> 4, l16 = lane & 15;
  int bm = blockIdx.x * 16;
  int wn = wave * 32;

  s16x8 Ah[4], Al[4];
#pragma unroll
  for (int ks = 0; ks < 4; ++ks) {
    const float4* xp = (const float4*)&x[(size_t)(bm + l16) * H + ks * 32 + quad * 8];
    float4 v0 = xp[0], v1 = xp[1];
    float vv[8] = {v0.x, v0.y, v0.z, v0.w, v1.x, v1.y, v1.z, v1.w};
#pragma unroll
    for (int j = 0; j < 8; ++j) {
      unsigned short hh = f2bf(vv[j]);
      Ah[ks][j] = (short)hh;
      Al[ks][j] = (short)f2bf(vv[j] - bf2f(hh));
    }
  }

  for (int ph = 0; ph < 3; ++ph) {
    const short* Bh = (ph == 0) ? Wqh : (ph == 1) ? Wkh : Wvh;
    const short* Bl = (ph == 0) ? Wql : Wkl;
    f32x4 acc[2];
    acc[0] = (f32x4){0.f, 0.f, 0.f, 0.f};
    acc[1] = (f32x4){0.f, 0.f, 0.f, 0.f};
    s16x8 B0[2][4];
#pragma unroll
    for (int nt = 0; nt < 2; ++nt)
#pragma unroll
      for (int ks = 0; ks < 4; ++ks)
        B0[nt][ks] = *(const s16x8*)&Bh[(size_t)(wn + nt * 16 + l16) * H + ks * 32 + quad * 8];
#pragma unroll
    for (int ks = 0; ks < 4; ++ks)
#pragma unroll
      for (int nt = 0; nt < 2; ++nt) {
        acc[nt] = __builtin_amdgcn_mfma_f32_16x16x32_bf16(Ah[ks], B0[nt][ks], acc[nt], 0, 0, 0);
        if (ph < 2)
          acc[nt] = __builtin_amdgcn_mfma_f32_16x16x32_bf16(Al[ks], B0[nt][ks], acc[nt], 0, 0, 0);
      }
    if (ph < 2) {
#pragma unroll
      for (int nt = 0; nt < 2; ++nt)
#pragma unroll
        for (int ks = 0; ks < 4; ++ks)
          B0[nt][ks] = *(const s16x8*)&Bl[(size_t)(wn + nt * 16 + l16) * H + ks * 32 + quad * 8];
#pragma unroll
      for (int ks = 0; ks < 4; ++ks)
#pragma unroll
        for (int nt = 0; nt < 2; ++nt)
          acc[nt] = __builtin_amdgcn_mfma_f32_16x16x32_bf16(Ah[ks], B0[nt][ks], acc[nt], 0, 0, 0);
      float* O = (ph == 0) ? Q : Km;
      const float* bias = (ph == 0) ? bq : bk;
#pragma unroll
      for (int nt = 0; nt < 2; ++nt) {
        int col = wn + nt * 16 + l16;
        float bb = bias[col];
#pragma unroll
        for (int r = 0; r < 4; ++r) {
          int row = bm + quad * 4 + r;
          O[(size_t)row * H + col] = acc[nt][r] + bb;
        }
      }
    } else {
#pragma unroll
      for (int nt = 0; nt < 2; ++nt) {
        int col = wn + nt * 16 + l16;
        float bb = bv[col];
#pragma unroll
        for (int r = 0; r < 4; ++r) {
          int row = bm + quad * 4 + r;
          Vbf[(size_t)row * H + col] = f2bf(acc[nt][r] + bb);
        }
      }
    }
  }
}

// ---------------------------------------------------------------------------
// FFN1: t1 = relu( BN1(h1) @ W1 + b1 ) -> bf16. LDS-free, barrier-free.
// grid (N/16, 2): blockIdx.y picks 128-col half.
// ---------------------------------------------------------------------------
__global__ __launch_bounds__(256) void ffn1_mfma(
    const float* __restrict__ h1, const short* __restrict__ W1h,
    const float* __restrict__ b1, const float* __restrict__ A1,
    const float* __restrict__ B1, unsigned short* __restrict__ t1)
{
  int tid = threadIdx.x;
  int wave = tid >> 6, lane = tid & 63;
  int quad = lane >> 4, l16 = lane & 15;
  int bm = blockIdx.x * 16, bn = blockIdx.y * 128;
  int wn = wave * 32;

  s16x8 Af[4];
#pragma unroll
  for (int ks = 0; ks < 4; ++ks) {
    int kof = ks * 32 + quad * 8;
    const float4* xp = (const float4*)&h1[(size_t)(bm + l16) * H + kof];
    float4 v0 = xp[0], v1 = xp[1];
    const float4* ap = (const float4*)&A1[kof];
    const float4* bp = (const float4*)&B1[kof];
    float4 a0 = ap[0], a1 = ap[1], b0 = bp[0], b1v = bp[1];
    float vv[8] = {a0.x * v0.x + b0.x, a0.y * v0.y + b0.y,
                   a0.z * v0.z + b0.z, a0.w * v0.w + b0.w,
                   a1.x * v1.x + b1v.x, a1.y * v1.y + b1v.y,
                   a1.z * v1.z + b1v.z, a1.w * v1.w + b1v.w};
#pragma unroll
    for (int j = 0; j < 8; ++j) Af[ks][j] = (short)f2bf(vv[j]);
  }

  f32x4 acc[2];
  acc[0] = (f32x4){0.f, 0.f, 0.f, 0.f};
  acc[1] = (f32x4){0.f, 0.f, 0.f, 0.f};
  s16x8 Bf[2][4];
#pragma unroll
  for (int nt = 0; nt < 2; ++nt)
#pragma unroll
    for (int ks = 0; ks < 4; ++ks)
      Bf[nt][ks] = *(const s16x8*)&W1h[(size_t)(bn + wn + nt * 16 + l16) * H + ks * 32 + quad * 8];
#pragma unroll
  for (int ks = 0; ks < 4; ++ks)
#pragma unroll
    for (int nt = 0; nt < 2; ++nt)
      acc[nt] = __builtin_amdgcn_mfma_f32_16x16x32_bf16(Af[ks], Bf[nt][ks], acc[nt], 0, 0, 0);

#pragma unroll
  for (int nt = 0; nt < 2; ++nt) {
    int col = bn + wn + nt * 16 + l16;
    float bb = b1[col];
#pragma unroll
    for (int r = 0; r < 4; ++r) {
      int row = bm + quad * 4 + r;
      float v = acc[nt][r] + bb;
      v = v > 0.f ? v : 0.f;
      t1[(size_t)row * H2 + col] = f2bf(v);
    }
  }
}

// ---------------------------------------------------------------------------
// FFN2: h2 = t1 @ W2 + b2 + BN1(h1). LDS-free, barrier-free. grid N/16.
// ---------------------------------------------------------------------------
__global__ __launch_bounds__(256) void ffn2_mfma(
    const unsigned short* __restrict__ t1, const short* __restrict__ W2h,
    const float* __restrict__ b2, const float* __restrict__ h1,
    const float* __restrict__ A1, const float* __restrict__ B1,
    float* __restrict__ h2)
{
  int tid = threadIdx.x;
  int wave = tid >> 6, lane = tid & 63;
  int quad = lane >> 4, l16 = lane & 15;
  int bm = blockIdx.x * 16;
  int wn = wave * 32;

  s16x8 Af[8];
#pragma unroll
  for (int ks = 0; ks < 8; ++ks)
    Af[ks] = *(const s16x8*)&t1[(size_t)(bm + l16) * H2 + ks * 32 + quad * 8];

  f32x4 acc[2];
  acc[0] = (f32x4){0.f, 0.f, 0.f, 0.f};
  acc[1] = (f32x4){0.f, 0.f, 0.f, 0.f};
  s16x8 Bf[2][8];
#pragma unroll
  for (int nt = 0; nt < 2; ++nt)
#pragma unroll
    for (int ks = 0; ks < 8; ++ks)
      Bf[nt][ks] = *(const s16x8*)&W2h[(size_t)(wn + nt * 16 + l16) * H2 + ks * 32 + quad * 8];
#pragma unroll
  for (int ks = 0; ks < 8; ++ks)
#pragma unroll
    for (int nt = 0; nt < 2; ++nt)
      acc[nt] = __builtin_amdgcn_mfma_f32_16x16x32_bf16(Af[ks], Bf[nt][ks], acc[nt], 0, 0, 0);

#pragma unroll
  for (int nt = 0; nt < 2; ++nt) {
    int col = wn + nt * 16 + l16;
    float bb = b2[col], ra = A1[col], rb = B1[col];
#pragma unroll
    for (int r = 0; r < 4; ++r) {
      int row = bm + quad * 4 + r;
      float rr = ra * h1[(size_t)row * H + col] + rb;
      h2[(size_t)row * H + col] = acc[nt][r] + bb + rr;
    }
  }
}

// ---------------------------------------------------------------------------
// Edge bias, coalesced BW-bound pass.
// ---------------------------------------------------------------------------
__global__ void eb_compute(const float* __restrict__ ea,
                           const float* __restrict__ We,
                           const float* __restrict__ be,
                           float* __restrict__ Eb, int E)
{
  int e = blockIdx.x * blockDim.x + threadIdx.x;
  if (e >= E) return;
  const float4* p = (const float4*)&ea[(size_t)e * 16];
  float4 w0 = *(const float4*)&We[0], w1 = *(const float4*)&We[4];
  float4 w2 = *(const float4*)&We[8], w3 = *(const float4*)&We[12];
  float4 a0 = p[0], a1 = p[1], a2 = p[2], a3 = p[3];
  float s = a0.x * w0.x + a0.y * w0.y + a0.z * w0.z + a0.w * w0.w
          + a1.x * w1.x + a1.y * w1.y + a1.z * w1.z + a1.w * w1.w
          + a2.x * w2.x + a2.y * w2.y + a2.z * w2.z + a2.w * w2.w
          + a3.x * w3.x + a3.y * w3.y + a3.z * w3.z + a3.w * w3.w;
  Eb[e] = s + be[0];
}

// ---------------------------------------------------------------------------
// XCD-grouped slab scatter: 8 src groups; 8 prefetched edges per thread.
// ---------------------------------------------------------------------------
__global__ void scatter8(const int* __restrict__ ei,
                         const float* __restrict__ Eb,
                         int* __restrict__ cnt,
                         int2* __restrict__ slabDE, int E, int N)
{
  int grp = blockIdx.x & 7;
  int blk = blockIdx.x >> 3;
  int lo = grp * (N >> 3), hi = lo + (N >> 3);
  int per = E >> 8;
  int base = blk * per;
  int srcs[8];
#pragma unroll
  for (int w = 0; w < 8; ++w) srcs[w] = ei[base + w * 256 + threadIdx.x];
#pragma unroll
  for (int w = 0; w < 8; ++w) {
    int src = srcs[w];
    if (src < lo || src >= hi) continue;
    int e = base + w * 256 + threadIdx.x;
    int dst = ei[E + e];
    float s = Eb[e];
    int pos = atomicAdd(&cnt[src], 1);
    if (pos < SLAB) {
      int2 rec; rec.x = dst; rec.y = __float_as_int(s);
      slabDE[src * SLAB + pos] = rec;
    }
  }
}

// ---------------------------------------------------------------------------
// Column sums of bf16 V (low-contention).
// ---------------------------------------------------------------------------
__global__ __launch_bounds__(128) void svsum(const unsigned short* __restrict__ Vbf,
                                             float* __restrict__ SV, int rowsPerBlock)
{
  int t = threadIdx.x;
  size_t r0 = (size_t)blockIdx.x * rowsPerBlock;
  float s = 0.f;
  for (int r = 0; r < rowsPerBlock; ++r) s += bf2f(Vbf[(r0 + r) * H + t]);
  atomicAdd(&SV[t], s);
}

// ---------------------------------------------------------------------------
// Fused per-row attention: scores (QK gather), dedup, sparse softmax vs
// dense-zero background, P@V (bf16 V), residual. 8 rows/block, 32 lanes/row.
// ---------------------------------------------------------------------------
__global__ __launch_bounds__(256) void rowfused(
    const float* __restrict__ x, const float* __restrict__ Q,
    const float* __restrict__ Km, const unsigned short* __restrict__ Vbf,
    const float* __restrict__ SV, const int* __restrict__ cnt,
    const int2* __restrict__ slabDE, float* __restrict__ h1, int N)
{
  __shared__ float sv[8][SLAB];
  __shared__ int sd[8][SLAB];
  __shared__ unsigned char sown[8][SLAB];
  int team = threadIdx.x >> 5, lane = threadIdx.x & 31;
  int i = blockIdx.x * 8 + team;
  int k = cnt[i]; if (k > SLAB) k = SLAB;
  int base = i * SLAB;

  // stage slab: sd = dst, sv = edge bias (seed)
  for (int p = lane; p < k; p += 32) {
    int2 de = slabDE[base + p];
    sd[team][p] = de.x;
    sv[team][p] = __int_as_float(de.y);
  }
  __syncthreads();

  // scoring: 4 subteams of 8 lanes, 2 edges each in flight
  int sub8 = lane & 7, sub4 = lane >> 3;
  const float4* q4 = (const float4*)(Q + (size_t)i * H);
  float4 qq0 = q4[sub8], qq1 = q4[8 + sub8], qq2 = q4[16 + sub8], qq3 = q4[24 + sub8];
  for (int p0 = sub4 * 2; p0 < k; p0 += 8) {
    int d0 = sd[team][p0];
    bool has1 = (p0 + 1 < k);
    int d1 = has1 ? sd[team][p0 + 1] : d0;
    const float4* k0 = (const float4*)(Km + (size_t)d0 * H);
    const float4* k1 = (const float4*)(Km + (size_t)d1 * H);
    float s0 = 0.f, s1 = 0.f;
    float4 a, b;
    a = k0[sub8];      b = k1[sub8];
    s0 += qq0.x * a.x + qq0.y * a.y + qq0.z * a.z + qq0.w * a.w;
    s1 += qq0.x * b.x + qq0.y * b.y + qq0.z * b.z + qq0.w * b.w;
    a = k0[8 + sub8];  b = k1[8 + sub8];
    s0 += qq1.x * a.x + qq1.y * a.y + qq1.z * a.z + qq1.w * a.w;
    s1 += qq1.x * b.x + qq1.y * b.y + qq1.z * b.z + qq1.w * b.w;
    a = k0[16 + sub8]; b = k1[16 + sub8];
    s0 += qq2.x * a.x + qq2.y * a.y + qq2.z * a.z + qq2.w * a.w;
    s1 += qq2.x * b.x + qq2.y * b.y + qq2.z * b.z + qq2.w * b.w;
    a = k0[24 + sub8]; b = k1[24 + sub8];
    s0 += qq3.x * a.x + qq3.y * a.y + qq3.z * a.z + qq3.w * a.w;
    s1 += qq3.x * b.x + qq3.y * b.y + qq3.z * b.z + qq3.w * b.w;
    s0 += __shfl_xor(s0, 1); s1 += __shfl_xor(s1, 1);
    s0 += __shfl_xor(s0, 2); s1 += __shfl_xor(s1, 2);
    s0 += __shfl_xor(s0, 4); s1 += __shfl_xor(s1, 4);
    if (sub8 == 0) {
      float t0 = s0 + sv[team][p0];
      sv[team][p0] = (t0 >= 0.f) ? t0 : 0.01f * t0;
      if (has1) {
        float t1v = s1 + sv[team][p0 + 1];
        sv[team][p0 + 1] = (t1v >= 0.f) ? t1v : 0.01f * t1v;
      }
    }
  }
  __syncthreads();

  // dedup: first slot with same dst owns; sum duplicate scores pre-exp
  for (int p = lane; p < k; p += 32) {
    int d = sd[team][p], o = p;
    for (int q = 0; q < p; ++q)
      if (sd[team][q] == d) { o = q; break; }
    sown[team][p] = (unsigned char)o;
  }
  __syncthreads();
  for (int p = lane; p < k; p += 32)
    if (sown[team][p] != (unsigned char)p)
      atomicAdd(&sv[team][sown[team][p]], sv[team][p]);
  __syncthreads();

  float m = 0.f;
  for (int p = lane; p < k; p += 32)
    if (sown[team][p] == (unsigned char)p) m = fmaxf(m, sv[team][p]);
#pragma unroll
  for (int mask = 16; mask; mask >>= 1) m = fmaxf(m, __shfl_xor(m, mask));
  float em = expf(-m);

  float zl = 0.f;
  for (int p = lane; p < k; p += 32) {
    float cf = 0.f;
    if (sown[team][p] == (unsigned char)p) cf = expf(sv[team][p] - m) - em;
    sv[team][p] = cf;
    zl += cf;
  }
#pragma unroll
  for (int mask = 16; mask; mask >>= 1) zl += __shfl_xor(zl, mask);
  float Zi = 1.f / ((float)N * em + zl);
  __syncthreads();

  const ushort4* V4 = (const ushort4*)Vbf;
  float4 s4 = *(const float4*)&SV[lane * 4];
  float ax = em * s4.x, ay = em * s4.y, az = em * s4.z, aw = em * s4.w;
  int c = 0;
  for (; c + 8 <= k; c += 8) {
    float cf[8]; int dd[8]; ushort4 vv[8];
#pragma unroll
    for (int u = 0; u < 8; ++u) { cf[u] = sv[team][c + u]; dd[u] = sd[team][c + u]; }
#pragma unroll
    for (int u = 0; u < 8; ++u) vv[u] = V4[(size_t)dd[u] * 32 + lane];
#pragma unroll
    for (int u = 0; u < 8; ++u) {
      ax += cf[u] * bf2f(vv[u].x);
      ay += cf[u] * bf2f(vv[u].y);
      az += cf[u] * bf2f(vv[u].z);
      aw += cf[u] * bf2f(vv[u].w);
    }
  }
  for (; c < k; ++c) {
    float cf = sv[team][c];
    ushort4 v0 = V4[(size_t)sd[team][c] * 32 + lane];
    ax += cf * bf2f(v0.x); ay += cf * bf2f(v0.y);
    az += cf * bf2f(v0.z); aw += cf * bf2f(v0.w);
  }
  float4 xx = *(const float4*)&x[(size_t)i * H + lane * 4];
  float4 out;
  out.x = xx.x + ax * Zi; out.y = xx.y + ay * Zi;
  out.z = xx.z + az * Zi; out.w = xx.w + aw * Zi;
  *(float4*)&h1[(size_t)i * H + lane * 4] = out;
}

// ---------------------------------------------------------------------------
__global__ __launch_bounds__(128) void colstats(
    const float* __restrict__ X, float* __restrict__ sum,
    float* __restrict__ sumsq, int rowsPerBlock)
{
  int t = threadIdx.x;
  size_t r0 = (size_t)blockIdx.x * rowsPerBlock;
  float s = 0.f, ss = 0.f;
  for (int r = 0; r < rowsPerBlock; ++r) {
    float v = X[(r0 + r) * H + t];
    s += v; ss += v * v;
  }
  atomicAdd(&sum[t], s);
  atomicAdd(&sumsq[t], ss);
}

__global__ void bn_final(const float* __restrict__ sum, const float* __restrict__ sumsq,
                         const float* __restrict__ g, const float* __restrict__ b,
                         float* __restrict__ A, float* __restrict__ B, int n)
{
  int t = threadIdx.x;
  float mu = sum[t] / (float)n;
  float var = sumsq[t] / (float)n - mu * mu;
  float rs = rsqrtf(var + 1e-5f);
  float a = g[t] * rs;
  A[t] = a;
  B[t] = b[t] - a * mu;
}

__global__ void bn_apply(const float* __restrict__ X, const float* __restrict__ A,
                         const float* __restrict__ B, float* __restrict__ Y, size_t n4)
{
  size_t i = (size_t)blockIdx.x * blockDim.x + threadIdx.x;
  if (i >= n4) return;
  float4 v = ((const float4*)X)[i];
  int c = (int)((i * 4) & (H - 1));
  float4 a = *(const float4*)&A[c];
  float4 b = *(const float4*)&B[c];
  v.x = a.x * v.x + b.x; v.y = a.y * v.y + b.y;
  v.z = a.z * v.z + b.z; v.w = a.w * v.w + b.w;
  ((float4*)Y)[i] = v;
}

// ---------------------------------------------------------------------------
extern "C" void kernel_launch(void* const* d_in, const int* in_sizes, int n_in,
                              void* d_out, int out_size, void* d_ws, size_t ws_size,
                              hipStream_t stream)
{
  const float* x  = (const float*)d_in[0];
  const int*   ei = (const int*)d_in[1];
  const float* ea = (const float*)d_in[2];
  const float* Wq = (const float*)d_in[3];
  const float* bq = (const float*)d_in[4];
  const float* Wk = (const float*)d_in[5];
  const float* bk = (const float*)d_in[6];
  const float* Wv = (const float*)d_in[7];
  const float* bv = (const float*)d_in[8];
  const float* We = (const float*)d_in[9];
  const float* be = (const float*)d_in[10];
  const float* g1 = (const float*)d_in[11];
  const float* bb1 = (const float*)d_in[12];
  const float* W1 = (const float*)d_in[13];
  const float* b1 = (const float*)d_in[14];
  const float* W2 = (const float*)d_in[15];
  const float* b2 = (const float*)d_in[16];
  const float* g2 = (const float*)d_in[17];
  const float* bb2 = (const float*)d_in[18];

  int N = in_sizes[0] / H;      // 16384
  int E = in_sizes[2] / 16;     // 524288
  size_t NH = (size_t)N * H;

  float* Q   = (float*)d_ws;                         // 8 MB
  float* Km  = Q + NH;                               // 8 MB
  float* h1  = Km + NH;                              // 8 MB
  unsigned short* Vbf = (unsigned short*)(h1 + NH);  // 4 MB
  int2*  slabDE = (int2*)(Vbf + NH);                 // 12 MB
  float* sAdead = (float*)(slabDE + (size_t)N * SLAB);  // 6 MB (spare)
  float* Eb     = sAdead + (size_t)N * SLAB;            // 2 MB
  int*   cnt    = (int*)(Eb + E);
  float* stats  = (float*)(cnt + N);
  float* SV   = stats;            // zeroed
  float* sum1 = stats + H;        // zeroed
  float* sq1  = stats + 2 * H;    // zeroed
  float* sum2 = stats + 3 * H;    // zeroed
  float* sq2  = stats + 4 * H;    // zeroed
  float* A1   = stats + 5 * H;
  float* B1   = stats + 6 * H;
  float* A2   = stats + 7 * H;
  float* B2   = stats + 8 * H;
  short* wbuf = (short*)(stats + 9 * H + 4);
  short* Wqh = wbuf;
  short* Wql = Wqh + 16384;
  short* Wkh = Wql + 16384;
  short* Wkl = Wkh + 16384;
  short* Wvh = Wkl + 16384;
  short* W1h = Wvh + 16384;
  short* W2h = W1h + 32768;
  unsigned short* t1 = (unsigned short*)Q;   // alias (Q dead after rowfused)
  float* h2 = Km;                            // alias (Km dead after rowfused)

  hipMemsetAsync(cnt, 0, (size_t)N * sizeof(int), stream);
  hipMemsetAsync(stats, 0, (size_t)5 * H * sizeof(float), stream);

  wprep<<<dim3(128, 1, 5), 256, 0, stream>>>(Wq, Wk, Wv, W1, W2,
      Wqh, Wql, Wkh, Wkl, Wvh, W1h, W2h);

  qkv_mfma<<<dim3(N / 16), 256, 0, stream>>>(
      x, Wqh, Wql, Wkh, Wkl, Wvh, bq, bk, bv, Q, Km, Vbf);

  eb_compute<<<dim3((E + 255) / 256), 256, 0, stream>>>(ea, We, be, Eb, E);
  scatter8<<<dim3(2048), 256, 0, stream>>>(ei, Eb, cnt, slabDE, E, N);
  svsum<<<dim3(128), 128, 0, stream>>>(Vbf, SV, N / 128);

  rowfused<<<dim3(N / 8), 256, 0, stream>>>(x, Q, Km, Vbf, SV, cnt, slabDE, h1, N);

  colstats<<<dim3(128), 128, 0, stream>>>(h1, sum1, sq1, N / 128);
  bn_final<<<dim3(1), H, 0, stream>>>(sum1, sq1, g1, bb1, A1, B1, N);

  ffn1_mfma<<<dim3(N / 16, 2), 256, 0, stream>>>(h1, W1h, b1, A1, B1, t1);
  ffn2_mfma<<<dim3(N / 16), 256, 0, stream>>>(t1, W2h, b2, h1, A1, B1, h2);

  colstats<<<dim3(128), 128, 0, stream>>>(h2, sum2, sq2, N / 128);
  bn_final<<<dim3(1), H, 0, stream>>>(sum2, sq2, g2, bb2, A2, B2, N);
  bn_apply<<<dim3((int)((NH / 4 + 255) / 256)), 256, 0, stream>>>(h2, A2, B2, (float*)d_out, NH / 4);
}

// Round 8
// 264.926 us; speedup vs baseline: 1.3781x; 1.3781x over previous
//
#include <hip/hip_runtime.h>
#include <hip/hip_bf16.h>
#include <math.h>

#define H 128
#define H2 256
#define SLAB 96    // slots per row; P(Poisson(32) > 96) ~ 1e-18
#define LDA 136    // LDS row pitch (shorts) for K=128 tiles
#define LDA2 264   // LDS row pitch (shorts) for K=256 tiles

typedef __attribute__((ext_vector_type(8))) short s16x8;
typedef __attribute__((ext_vector_type(4))) float f32x4;

__device__ __forceinline__ unsigned short f2bf(float f) {
  unsigned u = __float_as_uint(f);
  unsigned r = (u + 0x7FFFu + ((u >> 16) & 1u)) >> 16;
  return (unsigned short)r;
}
__device__ __forceinline__ float bf2f(unsigned short s) {
  return __uint_as_float(((unsigned)s) << 16);
}

// ---------------------------------------------------------------------------
// Weight prep: transpose to [n][k] + bf16 (split hi/lo for Wq, Wk).
// ---------------------------------------------------------------------------
__global__ void wprep(const float* __restrict__ Wq, const float* __restrict__ Wk,
                      const float* __restrict__ Wv, const float* __restrict__ W1,
                      const float* __restrict__ W2,
                      short* qh, short* ql, short* kh, short* kl,
                      short* vh, short* w1h, short* w2h)
{
  int job = blockIdx.z;
  const float* src; short* dh; short* dl = nullptr; int Kd, Nn;
  if (job == 0)      { src = Wq; dh = qh;  dl = ql; Kd = 128; Nn = 128; }
  else if (job == 1) { src = Wk; dh = kh;  dl = kl; Kd = 128; Nn = 128; }
  else if (job == 2) { src = Wv; dh = vh;           Kd = 128; Nn = 128; }
  else if (job == 3) { src = W1; dh = w1h;          Kd = 128; Nn = 256; }
  else               { src = W2; dh = w2h;          Kd = 256; Nn = 128; }
  int t = blockIdx.x * 256 + threadIdx.x;
  if (t >= Kd * Nn) return;
  int n = t / Kd, k = t - n * Kd;
  float v = src[(size_t)k * Nn + n];
  unsigned short h = f2bf(v);
  dh[t] = (short)h;
  if (dl) dl[t] = (short)f2bf(v - bf2f(h));
}

// ---------------------------------------------------------------------------
// QKV via MFMA. 64-row M-tile per block, 256 threads (4 waves x 32 cols).
// A (x) split hi/lo in staging; Q split-fp32 out, K split->bf16 out, V single.
// ONLY change vs 275us config: K output stored bf16 (L2-resident for score).
// ---------------------------------------------------------------------------
__global__ __launch_bounds__(256) void qkv_mfma(
    const float* __restrict__ x,
    const short* __restrict__ Wqh, const short* __restrict__ Wql,
    const short* __restrict__ Wkh, const short* __restrict__ Wkl,
    const short* __restrict__ Wvh,
    const float* __restrict__ bq, const float* __restrict__ bk,
    const float* __restrict__ bv,
    float* __restrict__ Q, unsigned short* __restrict__ Kbf,
    unsigned short* __restrict__ Vbf, float* __restrict__ SV)
{
  __shared__ __align__(16) short Ahi[64 * LDA];
  __shared__ __align__(16) short Alo[64 * LDA];
  __shared__ __align__(16) short Bhi[128 * LDA];
  __shared__ __align__(16) short Blo[128 * LDA];
  int tid = threadIdx.x;
  int bm = blockIdx.x * 64;
  int wave = tid >> 6, lane = tid & 63;
  int quad = lane >> 4, l16 = lane & 15;
  int wn = wave * 32;

  // stage A: 64x128 fp32 -> split bf16 hi/lo
#pragma unroll
  for (int i = 0; i < 4; ++i) {
    int g = i * 256 + tid;
    int row = g >> 4, f = g & 15;
    const float4* xp = (const float4*)&x[(size_t)(bm + row) * H + f * 8];
    float4 v0 = xp[0], v1 = xp[1];
    float vv[8] = {v0.x, v0.y, v0.z, v0.w, v1.x, v1.y, v1.z, v1.w};
    s16x8 hv, lv;
#pragma unroll
    for (int j = 0; j < 8; ++j) {
      unsigned short hh = f2bf(vv[j]);
      hv[j] = (short)hh;
      lv[j] = (short)f2bf(vv[j] - bf2f(hh));
    }
    *(s16x8*)&Ahi[row * LDA + f * 8] = hv;
    *(s16x8*)&Alo[row * LDA + f * 8] = lv;
  }

  for (int ph = 0; ph < 3; ++ph) {
    const short* Bh = (ph == 0) ? Wqh : (ph == 1) ? Wkh : Wvh;
    const short* Bl = (ph == 0) ? Wql : (ph == 1) ? Wkl : nullptr;
    if (ph > 0) __syncthreads();
#pragma unroll
    for (int i = 0; i < 8; ++i) {
      int g = i * 256 + tid;
      int n = g >> 4, f = g & 15;
      *(s16x8*)&Bhi[n * LDA + f * 8] = *(const s16x8*)&Bh[n * H + f * 8];
      if (Bl) *(s16x8*)&Blo[n * LDA + f * 8] = *(const s16x8*)&Bl[n * H + f * 8];
    }
    __syncthreads();

    f32x4 acc[4][2];
#pragma unroll
    for (int mt = 0; mt < 4; ++mt)
#pragma unroll
      for (int nt = 0; nt < 2; ++nt) acc[mt][nt] = (f32x4){0.f, 0.f, 0.f, 0.f};

#pragma unroll
    for (int ks = 0; ks < 4; ++ks) {
      int kof = ks * 32 + quad * 8;
      s16x8 ah[4], al[4], bh[2], bl2[2];
#pragma unroll
      for (int mt = 0; mt < 4; ++mt) {
        ah[mt] = *(s16x8*)&Ahi[(mt * 16 + l16) * LDA + kof];
        al[mt] = *(s16x8*)&Alo[(mt * 16 + l16) * LDA + kof];
      }
#pragma unroll
      for (int nt = 0; nt < 2; ++nt) {
        bh[nt] = *(s16x8*)&Bhi[(wn + nt * 16 + l16) * LDA + kof];
        bl2[nt] = *(s16x8*)&Blo[(wn + nt * 16 + l16) * LDA + kof];
      }
#pragma unroll
      for (int mt = 0; mt < 4; ++mt)
#pragma unroll
        for (int nt = 0; nt < 2; ++nt) {
          acc[mt][nt] = __builtin_amdgcn_mfma_f32_16x16x32_bf16(ah[mt], bh[nt], acc[mt][nt], 0, 0, 0);
          if (ph < 2) {
            acc[mt][nt] = __builtin_amdgcn_mfma_f32_16x16x32_bf16(ah[mt], bl2[nt], acc[mt][nt], 0, 0, 0);
            acc[mt][nt] = __builtin_amdgcn_mfma_f32_16x16x32_bf16(al[mt], bh[nt], acc[mt][nt], 0, 0, 0);
          }
        }
    }

    if (ph == 0) {
#pragma unroll
      for (int nt = 0; nt < 2; ++nt) {
        int col = wn + nt * 16 + l16;
        float bb = bq[col];
#pragma unroll
        for (int mt = 0; mt < 4; ++mt)
#pragma unroll
          for (int r = 0; r < 4; ++r) {
            int row = bm + mt * 16 + quad * 4 + r;
            Q[(size_t)row * H + col] = acc[mt][nt][r] + bb;
          }
      }
    } else if (ph == 1) {
#pragma unroll
      for (int nt = 0; nt < 2; ++nt) {
        int col = wn + nt * 16 + l16;
        float bb = bk[col];
#pragma unroll
        for (int mt = 0; mt < 4; ++mt)
#pragma unroll
          for (int r = 0; r < 4; ++r) {
            int row = bm + mt * 16 + quad * 4 + r;
            Kbf[(size_t)row * H + col] = f2bf(acc[mt][nt][r] + bb);
          }
      }
    } else {
#pragma unroll
      for (int nt = 0; nt < 2; ++nt) {
        int col = wn + nt * 16 + l16;
        float bb = bv[col];
        float ps = 0.f;
#pragma unroll
        for (int mt = 0; mt < 4; ++mt)
#pragma unroll
          for (int r = 0; r < 4; ++r) {
            int row = bm + mt * 16 + quad * 4 + r;
            float v = acc[mt][nt][r] + bb;
            Vbf[(size_t)row * H + col] = f2bf(v);
            ps += v;
          }
        ps += __shfl_xor(ps, 16);
        ps += __shfl_xor(ps, 32);
        if (quad == 0) atomicAdd(&SV[col], ps);
      }
    }
  }
}

// ---------------------------------------------------------------------------
// FFN1: t1 = relu( BN1(h1) @ W1 + b1 ) -> bf16. Single bf16, affine on A-load.
// ---------------------------------------------------------------------------
__global__ __launch_bounds__(256) void ffn1_mfma(
    const float* __restrict__ h1, const short* __restrict__ W1h,
    const float* __restrict__ b1, const float* __restrict__ A1,
    const float* __restrict__ B1, unsigned short* __restrict__ t1)
{
  __shared__ __align__(16) short As[64 * LDA];
  __shared__ __align__(16) short Bs[256 * LDA];
  int tid = threadIdx.x;
  int bm = blockIdx.x * 64;
  int wave = tid >> 6, lane = tid & 63;
  int quad = lane >> 4, l16 = lane & 15;
  int wn = wave * 64;

#pragma unroll
  for (int i = 0; i < 4; ++i) {
    int g = i * 256 + tid;
    int row = g >> 4, f = g & 15;
    const float4* xp = (const float4*)&h1[(size_t)(bm + row) * H + f * 8];
    float4 v0 = xp[0], v1 = xp[1];
    const float4* ap = (const float4*)&A1[f * 8];
    const float4* bp = (const float4*)&B1[f * 8];
    float4 a0 = ap[0], a1 = ap[1], b0 = bp[0], b1v = bp[1];
    float vv[8] = {a0.x * v0.x + b0.x, a0.y * v0.y + b0.y,
                   a0.z * v0.z + b0.z, a0.w * v0.w + b0.w,
                   a1.x * v1.x + b1v.x, a1.y * v1.y + b1v.y,
                   a1.z * v1.z + b1v.z, a1.w * v1.w + b1v.w};
    s16x8 hv;
#pragma unroll
    for (int j = 0; j < 8; ++j) hv[j] = (short)f2bf(vv[j]);
    *(s16x8*)&As[row * LDA + f * 8] = hv;
  }
#pragma unroll
  for (int i = 0; i < 16; ++i) {
    int g = i * 256 + tid;
    int n = g >> 4, f = g & 15;
    *(s16x8*)&Bs[n * LDA + f * 8] = *(const s16x8*)&W1h[n * H + f * 8];
  }
  __syncthreads();

  f32x4 acc[4][4];
#pragma unroll
  for (int mt = 0; mt < 4; ++mt)
#pragma unroll
    for (int nt = 0; nt < 4; ++nt) acc[mt][nt] = (f32x4){0.f, 0.f, 0.f, 0.f};

#pragma unroll
  for (int ks = 0; ks < 4; ++ks) {
    int kof = ks * 32 + quad * 8;
    s16x8 ah[4], bh[4];
#pragma unroll
    for (int mt = 0; mt < 4; ++mt) ah[mt] = *(s16x8*)&As[(mt * 16 + l16) * LDA + kof];
#pragma unroll
    for (int nt = 0; nt < 4; ++nt) bh[nt] = *(s16x8*)&Bs[(wn + nt * 16 + l16) * LDA + kof];
#pragma unroll
    for (int mt = 0; mt < 4; ++mt)
#pragma unroll
      for (int nt = 0; nt < 4; ++nt)
        acc[mt][nt] = __builtin_amdgcn_mfma_f32_16x16x32_bf16(ah[mt], bh[nt], acc[mt][nt], 0, 0, 0);
  }

#pragma unroll
  for (int nt = 0; nt < 4; ++nt) {
    int col = wn + nt * 16 + l16;
    float bb = b1[col];
#pragma unroll
    for (int mt = 0; mt < 4; ++mt)
#pragma unroll
      for (int r = 0; r < 4; ++r) {
        int row = bm + mt * 16 + quad * 4 + r;
        float v = acc[mt][nt][r] + bb;
        v = v > 0.f ? v : 0.f;
        t1[(size_t)row * H2 + col] = f2bf(v);
      }
  }
}

// ---------------------------------------------------------------------------
// FFN2: h2 = t1 @ W2 + b2 + BN1(h1); fused BN2 column sum/sumsq.
// ---------------------------------------------------------------------------
__global__ __launch_bounds__(256) void ffn2_mfma(
    const unsigned short* __restrict__ t1, const short* __restrict__ W2h,
    const float* __restrict__ b2, const float* __restrict__ h1,
    const float* __restrict__ A1, const float* __restrict__ B1,
    float* __restrict__ h2, float* __restrict__ sum2, float* __restrict__ sq2)
{
  __shared__ __align__(16) short As[64 * LDA2];
  __shared__ __align__(16) short Bs[128 * LDA2];
  int tid = threadIdx.x;
  int bm = blockIdx.x * 64;
  int wave = tid >> 6, lane = tid & 63;
  int quad = lane >> 4, l16 = lane & 15;
  int wn = wave * 32;

#pragma unroll
  for (int i = 0; i < 8; ++i) {
    int g = i * 256 + tid;
    int row = g >> 5, f = g & 31;
    *(s16x8*)&As[row * LDA2 + f * 8] = *(const s16x8*)&t1[(size_t)(bm + row) * H2 + f * 8];
  }
#pragma unroll
  for (int i = 0; i < 16; ++i) {
    int g = i * 256 + tid;
    int n = g >> 5, f = g & 31;
    *(s16x8*)&Bs[n * LDA2 + f * 8] = *(const s16x8*)&W2h[n * H2 + f * 8];
  }
  __syncthreads();

  f32x4 acc[4][2];
#pragma unroll
  for (int mt = 0; mt < 4; ++mt)
#pragma unroll
    for (int nt = 0; nt < 2; ++nt) acc[mt][nt] = (f32x4){0.f, 0.f, 0.f, 0.f};

#pragma unroll
  for (int ks = 0; ks < 8; ++ks) {
    int kof = ks * 32 + quad * 8;
    s16x8 ah[4], bh[2];
#pragma unroll
    for (int mt = 0; mt < 4; ++mt) ah[mt] = *(s16x8*)&As[(mt * 16 + l16) * LDA2 + kof];
#pragma unroll
    for (int nt = 0; nt < 2; ++nt) bh[nt] = *(s16x8*)&Bs[(wn + nt * 16 + l16) * LDA2 + kof];
#pragma unroll
    for (int mt = 0; mt < 4; ++mt)
#pragma unroll
      for (int nt = 0; nt < 2; ++nt)
        acc[mt][nt] = __builtin_amdgcn_mfma_f32_16x16x32_bf16(ah[mt], bh[nt], acc[mt][nt], 0, 0, 0);
  }

#pragma unroll
  for (int nt = 0; nt < 2; ++nt) {
    int col = wn + nt * 16 + l16;
    float bb = b2[col], ra = A1[col], rb = B1[col];
    float ps = 0.f, pq = 0.f;
#pragma unroll
    for (int mt = 0; mt < 4; ++mt)
#pragma unroll
      for (int r = 0; r < 4; ++r) {
        int row = bm + mt * 16 + quad * 4 + r;
        float rr = ra * h1[(size_t)row * H + col] + rb;
        float v = acc[mt][nt][r] + bb + rr;
        h2[(size_t)row * H + col] = v;
        ps += v; pq += v * v;
      }
    ps += __shfl_xor(ps, 16); ps += __shfl_xor(ps, 32);
    pq += __shfl_xor(pq, 16); pq += __shfl_xor(pq, 32);
    if (quad == 0) {
      atomicAdd(&sum2[col], ps);
      atomicAdd(&sq2[col], pq);
    }
  }
}

// ---------------------------------------------------------------------------
// XCD-grouped edge scatter: 8 groups, each owns N/8 rows, scans all edges,
// writes only its own slab region (keeps dirty lines in one L2).
// ---------------------------------------------------------------------------
__global__ void ebfill(const float* __restrict__ ea,
                       const float* __restrict__ We,
                       const float* __restrict__ be,
                       const int* __restrict__ ei,
                       int* __restrict__ cnt,
                       int2* __restrict__ slabDE, int E, int N)
{
  int grp = blockIdx.x & 7;
  int blk = blockIdx.x >> 3;
  int lo = grp * (N >> 3), hi = lo + (N >> 3);
  int per = E >> 8;                 // edges per window (2048)
  int base = blk * per;
  float4 w0 = *(const float4*)&We[0], w1 = *(const float4*)&We[4];
  float4 w2 = *(const float4*)&We[8], w3 = *(const float4*)&We[12];
  float bias = be[0];
  for (int i = 0; i < per; i += 256) {
    int e = base + i + threadIdx.x;
    if (e >= E) continue;
    int src = ei[e];
    if (src < lo || src >= hi) continue;
    int dst = ei[E + e];
    const float4* p = (const float4*)&ea[(size_t)e * 16];
    float4 a0 = p[0], a1 = p[1], a2 = p[2], a3 = p[3];
    float s = a0.x * w0.x + a0.y * w0.y + a0.z * w0.z + a0.w * w0.w
            + a1.x * w1.x + a1.y * w1.y + a1.z * w1.z + a1.w * w1.w
            + a2.x * w2.x + a2.y * w2.y + a2.z * w2.z + a2.w * w2.w
            + a3.x * w3.x + a3.y * w3.y + a3.z * w3.z + a3.w * w3.w;
    s += bias;
    int pos = atomicAdd(&cnt[src], 1);
    if (pos < SLAB) {
      int2 rec; rec.x = dst; rec.y = __float_as_int(s);
      slabDE[src * SLAB + pos] = rec;
    }
  }
}

// ---------------------------------------------------------------------------
// Slab scores: 2 rows/block, 16 teams of 8 lanes per row, 2 edges per team.
// K gathered as bf16 (4 MB, per-XCD L2 resident); Q fp32.
// ---------------------------------------------------------------------------
__global__ __launch_bounds__(256) void score_slab(
    const float* __restrict__ Q, const unsigned short* __restrict__ Kbf,
    const int* __restrict__ cnt, const int2* __restrict__ slabDE,
    float* __restrict__ sAslab, int N)
{
  int tid = threadIdx.x;
  int team = tid >> 3, sub = tid & 7;
  int local = team & 15;
  int i = blockIdx.x * 2 + (team >> 4);
  int k = cnt[i]; if (k > SLAB) k = SLAB;
  const float4* q4 = (const float4*)(Q + (size_t)i * H);
  // lane sub covers elements [sub*8, sub*8+8) and [64+sub*8, 64+sub*8+8)
  float4 qa0 = q4[2 * sub], qa1 = q4[2 * sub + 1];
  float4 qb0 = q4[16 + 2 * sub], qb1 = q4[17 + 2 * sub];
  int base = i * SLAB;

  for (int p = local * 2; p < k; p += 32) {
    int2 de0 = slabDE[base + p];
    bool has1 = (p + 1 < k);
    int2 de1 = has1 ? slabDE[base + p + 1] : de0;
    const s16x8* k0 = (const s16x8*)(Kbf + (size_t)de0.x * H);
    const s16x8* k1 = (const s16x8*)(Kbf + (size_t)de1.x * H);
    s16x8 ka0 = k0[sub], kb0 = k0[8 + sub];
    s16x8 ka1 = k1[sub], kb1 = k1[8 + sub];
    float p0, p1;
    p0 = qa0.x * bf2f((unsigned short)ka0[0]) + qa0.y * bf2f((unsigned short)ka0[1])
       + qa0.z * bf2f((unsigned short)ka0[2]) + qa0.w * bf2f((unsigned short)ka0[3])
       + qa1.x * bf2f((unsigned short)ka0[4]) + qa1.y * bf2f((unsigned short)ka0[5])
       + qa1.z * bf2f((unsigned short)ka0[6]) + qa1.w * bf2f((unsigned short)ka0[7])
       + qb0.x * bf2f((unsigned short)kb0[0]) + qb0.y * bf2f((unsigned short)kb0[1])
       + qb0.z * bf2f((unsigned short)kb0[2]) + qb0.w * bf2f((unsigned short)kb0[3])
       + qb1.x * bf2f((unsigned short)kb0[4]) + qb1.y * bf2f((unsigned short)kb0[5])
       + qb1.z * bf2f((unsigned short)kb0[6]) + qb1.w * bf2f((unsigned short)kb0[7]);
    p1 = qa0.x * bf2f((unsigned short)ka1[0]) + qa0.y * bf2f((unsigned short)ka1[1])
       + qa0.z * bf2f((unsigned short)ka1[2]) + qa0.w * bf2f((unsigned short)ka1[3])
       + qa1.x * bf2f((unsigned short)ka1[4]) + qa1.y * bf2f((unsigned short)ka1[5])
       + qa1.z * bf2f((unsigned short)ka1[6]) + qa1.w * bf2f((unsigned short)ka1[7])
       + qb0.x * bf2f((unsigned short)kb1[0]) + qb0.y * bf2f((unsigned short)kb1[1])
       + qb0.z * bf2f((unsigned short)kb1[2]) + qb0.w * bf2f((unsigned short)kb1[3])
       + qb1.x * bf2f((unsigned short)kb1[4]) + qb1.y * bf2f((unsigned short)kb1[5])
       + qb1.z * bf2f((unsigned short)kb1[6]) + qb1.w * bf2f((unsigned short)kb1[7]);
    p0 += __shfl_xor(p0, 1); p1 += __shfl_xor(p1, 1);
    p0 += __shfl_xor(p0, 2); p1 += __shfl_xor(p1, 2);
    p0 += __shfl_xor(p0, 4); p1 += __shfl_xor(p1, 4);
    if (sub == 0) {
      float s0 = p0 + __int_as_float(de0.y);
      sAslab[base + p] = (s0 >= 0.f) ? s0 : 0.01f * s0;
      if (has1) {
        float s1 = p1 + __int_as_float(de1.y);
        sAslab[base + p + 1] = (s1 >= 0.f) ? s1 : 0.01f * s1;
      }
    }
  }
}

// ---------------------------------------------------------------------------
// Per-row: dedup, sparse softmax vs dense-zero background, P@V (bf16 V),
// fused residual. 32 lanes per row, 8 rows/block.
// ---------------------------------------------------------------------------
__global__ __launch_bounds__(256) void row_slab(
    const float* __restrict__ x, const unsigned short* __restrict__ Vbf,
    const float* __restrict__ SV, const int* __restrict__ cnt,
    const float* __restrict__ sAslab, const int2* __restrict__ slabDE,
    float* __restrict__ h1, int N)
{
  __shared__ float sv[8][SLAB];
  __shared__ int sd[8][SLAB];
  __shared__ unsigned char sown[8][SLAB];
  int team = threadIdx.x >> 5, lane = threadIdx.x & 31;
  int i = blockIdx.x * 8 + team;
  int k = cnt[i]; if (k > SLAB) k = SLAB;
  int base = i * SLAB;

  for (int p = lane; p < k; p += 32) {
    sv[team][p] = sAslab[base + p];
    sd[team][p] = slabDE[base + p].x;
  }
  __syncthreads();

  for (int p = lane; p < k; p += 32) {
    int d = sd[team][p], o = p;
    for (int q = 0; q < p; ++q)
      if (sd[team][q] == d) { o = q; break; }
    sown[team][p] = (unsigned char)o;
  }
  __syncthreads();
  for (int p = lane; p < k; p += 32)
    if (sown[team][p] != (unsigned char)p)
      atomicAdd(&sv[team][sown[team][p]], sv[team][p]);
  __syncthreads();

  float m = 0.f;
  for (int p = lane; p < k; p += 32)
    if (sown[team][p] == (unsigned char)p) m = fmaxf(m, sv[team][p]);
#pragma unroll
  for (int mask = 16; mask; mask >>= 1) m = fmaxf(m, __shfl_xor(m, mask));
  float em = expf(-m);

  float zl = 0.f;
  for (int p = lane; p < k; p += 32) {
    float cf = 0.f;
    if (sown[team][p] == (unsigned char)p) cf = expf(sv[team][p] - m) - em;
    sv[team][p] = cf;
    zl += cf;
  }
#pragma unroll
  for (int mask = 16; mask; mask >>= 1) zl += __shfl_xor(zl, mask);
  float Zi = 1.f / ((float)N * em + zl);
  __syncthreads();

  const ushort4* V4 = (const ushort4*)Vbf;
  float4 s4 = *(const float4*)&SV[lane * 4];
  float ax = em * s4.x, ay = em * s4.y, az = em * s4.z, aw = em * s4.w;
  int c = 0;
  for (; c + 8 <= k; c += 8) {
    float cf[8]; int dd[8]; ushort4 vv[8];
#pragma unroll
    for (int u = 0; u < 8; ++u) { cf[u] = sv[team][c + u]; dd[u] = sd[team][c + u]; }
#pragma unroll
    for (int u = 0; u < 8; ++u) vv[u] = V4[(size_t)dd[u] * 32 + lane];
#pragma unroll
    for (int u = 0; u < 8; ++u) {
      ax += cf[u] * bf2f(vv[u].x);
      ay += cf[u] * bf2f(vv[u].y);
      az += cf[u] * bf2f(vv[u].z);
      aw += cf[u] * bf2f(vv[u].w);
    }
  }
  for (; c < k; ++c) {
    float cf = sv[team][c];
    ushort4 v0 = V4[(size_t)sd[team][c] * 32 + lane];
    ax += cf * bf2f(v0.x); ay += cf * bf2f(v0.y);
    az += cf * bf2f(v0.z); aw += cf * bf2f(v0.w);
  }
  float4 xx = *(const float4*)&x[(size_t)i * H + lane * 4];
  float4 out;
  out.x = xx.x + ax * Zi; out.y = xx.y + ay * Zi;
  out.z = xx.z + az * Zi; out.w = xx.w + aw * Zi;
  *(float4*)&h1[(size_t)i * H + lane * 4] = out;
}

// ---------------------------------------------------------------------------
__global__ __launch_bounds__(128) void colstats(
    const float* __restrict__ X, float* __restrict__ sum,
    float* __restrict__ sumsq, int rowsPerBlock)
{
  int t = threadIdx.x;
  size_t r0 = (size_t)blockIdx.x * rowsPerBlock;
  float s = 0.f, ss = 0.f;
  for (int r = 0; r < rowsPerBlock; ++r) {
    float v = X[(r0 + r) * H + t];
    s += v; ss += v * v;
  }
  atomicAdd(&sum[t], s);
  atomicAdd(&sumsq[t], ss);
}

__global__ void bn_final(const float* __restrict__ sum, const float* __restrict__ sumsq,
                         const float* __restrict__ g, const float* __restrict__ b,
                         float* __restrict__ A, float* __restrict__ B, int n)
{
  int t = threadIdx.x;
  float mu = sum[t] / (float)n;
  float var = sumsq[t] / (float)n - mu * mu;
  float rs = rsqrtf(var + 1e-5f);
  float a = g[t] * rs;
  A[t] = a;
  B[t] = b[t] - a * mu;
}

__global__ void bn_apply(const float* __restrict__ X, const float* __restrict__ A,
                         const float* __restrict__ B, float* __restrict__ Y, size_t n4)
{
  size_t i = (size_t)blockIdx.x * blockDim.x + threadIdx.x;
  if (i >= n4) return;
  float4 v = ((const float4*)X)[i];
  int c = (int)((i * 4) & (H - 1));
  float4 a = *(const float4*)&A[c];
  float4 b = *(const float4*)&B[c];
  v.x = a.x * v.x + b.x; v.y = a.y * v.y + b.y;
  v.z = a.z * v.z + b.z; v.w = a.w * v.w + b.w;
  ((float4*)Y)[i] = v;
}

// ---------------------------------------------------------------------------
extern "C" void kernel_launch(void* const* d_in, const int* in_sizes, int n_in,
                              void* d_out, int out_size, void* d_ws, size_t ws_size,
                              hipStream_t stream)
{
  const float* x  = (const float*)d_in[0];
  const int*   ei = (const int*)d_in[1];
  const float* ea = (const float*)d_in[2];
  const float* Wq = (const float*)d_in[3];
  const float* bq = (const float*)d_in[4];
  const float* Wk = (const float*)d_in[5];
  const float* bk = (const float*)d_in[6];
  const float* Wv = (const float*)d_in[7];
  const float* bv = (const float*)d_in[8];
  const float* We = (const float*)d_in[9];
  const float* be = (const float*)d_in[10];
  const float* g1 = (const float*)d_in[11];
  const float* bb1 = (const float*)d_in[12];
  const float* W1 = (const float*)d_in[13];
  const float* b1 = (const float*)d_in[14];
  const float* W2 = (const float*)d_in[15];
  const float* b2 = (const float*)d_in[16];
  const float* g2 = (const float*)d_in[17];
  const float* bb2 = (const float*)d_in[18];

  int N = in_sizes[0] / H;      // 16384
  int E = in_sizes[2] / 16;     // 524288
  size_t NH = (size_t)N * H;

  float* Q   = (float*)d_ws;                         // 8 MB
  float* KmSlot = Q + NH;                            // 8 MB (Kbf + later h2)
  float* h1  = KmSlot + NH;                          // 8 MB
  unsigned short* Vbf = (unsigned short*)(h1 + NH);  // 4 MB
  int2*  slabDE = (int2*)(Vbf + NH);                 // 12 MB
  float* sAslab = (float*)(slabDE + (size_t)N * SLAB);  // 6 MB
  int*   cnt    = (int*)(sAslab + (size_t)N * SLAB);
  float* stats  = (float*)(cnt + N);
  float* SV   = stats;            // zeroed
  float* sum1 = stats + H;        // zeroed
  float* sq1  = stats + 2 * H;    // zeroed
  float* sum2 = stats + 3 * H;    // zeroed
  float* sq2  = stats + 4 * H;    // zeroed
  float* A1   = stats + 5 * H;
  float* B1   = stats + 6 * H;
  float* A2   = stats + 7 * H;
  float* B2   = stats + 8 * H;
  short* wbuf = (short*)(stats + 9 * H + 4);
  short* Wqh = wbuf;
  short* Wql = Wqh + 16384;
  short* Wkh = Wql + 16384;
  short* Wkl = Wkh + 16384;
  short* Wvh = Wkl + 16384;
  short* W1h = Wvh + 16384;
  short* W2h = W1h + 32768;
  unsigned short* Kbf = (unsigned short*)KmSlot;  // 4 MB, dead after score_slab
  unsigned short* t1 = (unsigned short*)Q;        // alias (Q dead after score_slab)
  float* h2 = KmSlot;                             // alias (Kbf dead after score_slab)

  hipMemsetAsync(cnt, 0, (size_t)N * sizeof(int), stream);
  hipMemsetAsync(stats, 0, (size_t)5 * H * sizeof(float), stream);

  wprep<<<dim3(128, 1, 5), 256, 0, stream>>>(Wq, Wk, Wv, W1, W2,
      Wqh, Wql, Wkh, Wkl, Wvh, W1h, W2h);

  qkv_mfma<<<dim3(N / 64), 256, 0, stream>>>(
      x, Wqh, Wql, Wkh, Wkl, Wvh, bq, bk, bv, Q, Kbf, Vbf, SV);

  ebfill<<<dim3(2048), 256, 0, stream>>>(ea, We, be, ei, cnt, slabDE, E, N);
  score_slab<<<dim3(N / 2), 256, 0, stream>>>(Q, Kbf, cnt, slabDE, sAslab, N);
  row_slab<<<dim3(N / 8), 256, 0, stream>>>(x, Vbf, SV, cnt, sAslab, slabDE, h1, N);

  colstats<<<dim3(128), 128, 0, stream>>>(h1, sum1, sq1, N / 128);
  bn_final<<<dim3(1), H, 0, stream>>>(sum1, sq1, g1, bb1, A1, B1, N);

  ffn1_mfma<<<dim3(N / 64), 256, 0, stream>>>(h1, W1h, b1, A1, B1, t1);
  ffn2_mfma<<<dim3(N / 64), 256, 0, stream>>>(t1, W2h, b2, h1, A1, B1, h2, sum2, sq2);

  bn_final<<<dim3(1), H, 0, stream>>>(sum2, sq2, g2, bb2, A2, B2, N);
  bn_apply<<<dim3((int)((NH / 4 + 255) / 256)), 256, 0, stream>>>(h2, A2, B2, (float*)d_out, NH / 4);
}

// Round 9
// 262.564 us; speedup vs baseline: 1.3905x; 1.0090x over previous
//
#include <hip/hip_runtime.h>
#include <hip/hip_bf16.h>
#include <math.h>

#define H 128
#define H2 256
#define SLAB 96    // slots per row; P(Poisson(32) > 96) ~ 1e-18
#define LDA 136    // LDS row pitch (shorts) for K=128 tiles
#define LDA2 264   // LDS row pitch (shorts) for K=256 tiles
#define EPS 1e-5f

typedef __attribute__((ext_vector_type(8))) short s16x8;
typedef __attribute__((ext_vector_type(4))) float f32x4;

__device__ __forceinline__ unsigned short f2bf(float f) {
  unsigned u = __float_as_uint(f);
  unsigned r = (u + 0x7FFFu + ((u >> 16) & 1u)) >> 16;
  return (unsigned short)r;
}
__device__ __forceinline__ float bf2f(unsigned short s) {
  return __uint_as_float(((unsigned)s) << 16);
}

// ---------------------------------------------------------------------------
// Weight prep: transpose to [n][k] + bf16 (split hi/lo for Wq, Wk).
// ---------------------------------------------------------------------------
__global__ void wprep(const float* __restrict__ Wq, const float* __restrict__ Wk,
                      const float* __restrict__ Wv, const float* __restrict__ W1,
                      const float* __restrict__ W2,
                      short* qh, short* ql, short* kh, short* kl,
                      short* vh, short* w1h, short* w2h)
{
  int job = blockIdx.z;
  const float* src; short* dh; short* dl = nullptr; int Kd, Nn;
  if (job == 0)      { src = Wq; dh = qh;  dl = ql; Kd = 128; Nn = 128; }
  else if (job == 1) { src = Wk; dh = kh;  dl = kl; Kd = 128; Nn = 128; }
  else if (job == 2) { src = Wv; dh = vh;           Kd = 128; Nn = 128; }
  else if (job == 3) { src = W1; dh = w1h;          Kd = 128; Nn = 256; }
  else               { src = W2; dh = w2h;          Kd = 256; Nn = 128; }
  int t = blockIdx.x * 256 + threadIdx.x;
  if (t >= Kd * Nn) return;
  int n = t / Kd, k = t - n * Kd;
  float v = src[(size_t)k * Nn + n];
  unsigned short h = f2bf(v);
  dh[t] = (short)h;
  if (dl) dl[t] = (short)f2bf(v - bf2f(h));
}

// ---------------------------------------------------------------------------
// QKV via MFMA. 64-row M-tile, 256 threads (4 waves x 32 cols).
// A (x) split hi/lo staged ONCE in LDS (35 KB); B fragments loaded directly
// from L2-hot [n][k] bf16 weights (no B LDS, no per-phase barriers).
// Q fp32 out; K bf16 out (L2-resident for score); V bf16 + SV column sums.
// ---------------------------------------------------------------------------
__global__ __launch_bounds__(256) void qkv_mfma(
    const float* __restrict__ x,
    const short* __restrict__ Wqh, const short* __restrict__ Wql,
    const short* __restrict__ Wkh, const short* __restrict__ Wkl,
    const short* __restrict__ Wvh,
    const float* __restrict__ bq, const float* __restrict__ bk,
    const float* __restrict__ bv,
    float* __restrict__ Q, unsigned short* __restrict__ Kbf,
    unsigned short* __restrict__ Vbf, float* __restrict__ SV)
{
  __shared__ __align__(16) short Ahi[64 * LDA];
  __shared__ __align__(16) short Alo[64 * LDA];
  int tid = threadIdx.x;
  int bm = blockIdx.x * 64;
  int wave = tid >> 6, lane = tid & 63;
  int quad = lane >> 4, l16 = lane & 15;
  int wn = wave * 32;

  // stage A: 64x128 fp32 -> split bf16 hi/lo (once)
#pragma unroll
  for (int i = 0; i < 4; ++i) {
    int g = i * 256 + tid;
    int row = g >> 4, f = g & 15;
    const float4* xp = (const float4*)&x[(size_t)(bm + row) * H + f * 8];
    float4 v0 = xp[0], v1 = xp[1];
    float vv[8] = {v0.x, v0.y, v0.z, v0.w, v1.x, v1.y, v1.z, v1.w};
    s16x8 hv, lv;
#pragma unroll
    for (int j = 0; j < 8; ++j) {
      unsigned short hh = f2bf(vv[j]);
      hv[j] = (short)hh;
      lv[j] = (short)f2bf(vv[j] - bf2f(hh));
    }
    *(s16x8*)&Ahi[row * LDA + f * 8] = hv;
    *(s16x8*)&Alo[row * LDA + f * 8] = lv;
  }
  __syncthreads();

  for (int ph = 0; ph < 3; ++ph) {
    const short* Bh = (ph == 0) ? Wqh : (ph == 1) ? Wkh : Wvh;
    const short* Bl = (ph == 0) ? Wql : (ph == 1) ? Wkl : nullptr;

    s16x8 bh[2][4], bl2[2][4];
#pragma unroll
    for (int nt = 0; nt < 2; ++nt)
#pragma unroll
      for (int ks = 0; ks < 4; ++ks)
        bh[nt][ks] = *(const s16x8*)&Bh[(size_t)(wn + nt * 16 + l16) * H + ks * 32 + quad * 8];
    if (Bl) {
#pragma unroll
      for (int nt = 0; nt < 2; ++nt)
#pragma unroll
        for (int ks = 0; ks < 4; ++ks)
          bl2[nt][ks] = *(const s16x8*)&Bl[(size_t)(wn + nt * 16 + l16) * H + ks * 32 + quad * 8];
    }

    f32x4 acc[4][2];
#pragma unroll
    for (int mt = 0; mt < 4; ++mt)
#pragma unroll
      for (int nt = 0; nt < 2; ++nt) acc[mt][nt] = (f32x4){0.f, 0.f, 0.f, 0.f};

#pragma unroll
    for (int ks = 0; ks < 4; ++ks) {
      int kof = ks * 32 + quad * 8;
      s16x8 ah[4], al[4];
#pragma unroll
      for (int mt = 0; mt < 4; ++mt) {
        ah[mt] = *(s16x8*)&Ahi[(mt * 16 + l16) * LDA + kof];
        al[mt] = *(s16x8*)&Alo[(mt * 16 + l16) * LDA + kof];
      }
#pragma unroll
      for (int mt = 0; mt < 4; ++mt)
#pragma unroll
        for (int nt = 0; nt < 2; ++nt) {
          acc[mt][nt] = __builtin_amdgcn_mfma_f32_16x16x32_bf16(ah[mt], bh[nt][ks], acc[mt][nt], 0, 0, 0);
          if (ph < 2) {
            acc[mt][nt] = __builtin_amdgcn_mfma_f32_16x16x32_bf16(ah[mt], bl2[nt][ks], acc[mt][nt], 0, 0, 0);
            acc[mt][nt] = __builtin_amdgcn_mfma_f32_16x16x32_bf16(al[mt], bh[nt][ks], acc[mt][nt], 0, 0, 0);
          }
        }
    }

    if (ph == 0) {
#pragma unroll
      for (int nt = 0; nt < 2; ++nt) {
        int col = wn + nt * 16 + l16;
        float bb = bq[col];
#pragma unroll
        for (int mt = 0; mt < 4; ++mt)
#pragma unroll
          for (int r = 0; r < 4; ++r) {
            int row = bm + mt * 16 + quad * 4 + r;
            Q[(size_t)row * H + col] = acc[mt][nt][r] + bb;
          }
      }
    } else if (ph == 1) {
#pragma unroll
      for (int nt = 0; nt < 2; ++nt) {
        int col = wn + nt * 16 + l16;
        float bb = bk[col];
#pragma unroll
        for (int mt = 0; mt < 4; ++mt)
#pragma unroll
          for (int r = 0; r < 4; ++r) {
            int row = bm + mt * 16 + quad * 4 + r;
            Kbf[(size_t)row * H + col] = f2bf(acc[mt][nt][r] + bb);
          }
      }
    } else {
#pragma unroll
      for (int nt = 0; nt < 2; ++nt) {
        int col = wn + nt * 16 + l16;
        float bb = bv[col];
        float ps = 0.f;
#pragma unroll
        for (int mt = 0; mt < 4; ++mt)
#pragma unroll
          for (int r = 0; r < 4; ++r) {
            int row = bm + mt * 16 + quad * 4 + r;
            float v = acc[mt][nt][r] + bb;
            Vbf[(size_t)row * H + col] = f2bf(v);
            ps += v;
          }
        ps += __shfl_xor(ps, 16);
        ps += __shfl_xor(ps, 32);
        if (quad == 0) atomicAdd(&SV[col], ps);
      }
    }
  }
}

// ---------------------------------------------------------------------------
// FFN1: t1 = relu( BN1(h1) @ W1 + b1 ) -> bf16. BN1 affine computed inline
// from sum1/sq1 (replaces bn_final dispatch). LDS = A tile only (17 KB).
// ---------------------------------------------------------------------------
__global__ __launch_bounds__(256) void ffn1_mfma(
    const float* __restrict__ h1, const short* __restrict__ W1h,
    const float* __restrict__ b1,
    const float* __restrict__ sum1, const float* __restrict__ sq1,
    const float* __restrict__ g1, const float* __restrict__ bb1,
    unsigned short* __restrict__ t1, float invN)
{
  __shared__ __align__(16) short As[64 * LDA];
  int tid = threadIdx.x;
  int bm = blockIdx.x * 64;
  int wave = tid >> 6, lane = tid & 63;
  int quad = lane >> 4, l16 = lane & 15;
  int wn = wave * 64;

  // per-thread BN1 affine for its 8 staged k-columns (f constant across iters)
  int f = tid & 15;
  float aP[8], bP[8];
#pragma unroll
  for (int j = 0; j < 8; ++j) {
    int c = f * 8 + j;
    float mu = sum1[c] * invN;
    float var = sq1[c] * invN - mu * mu;
    float rs = rsqrtf(var + EPS);
    float a = g1[c] * rs;
    aP[j] = a;
    bP[j] = bb1[c] - a * mu;
  }

#pragma unroll
  for (int i = 0; i < 4; ++i) {
    int g = i * 256 + tid;
    int row = g >> 4;
    const float4* xp = (const float4*)&h1[(size_t)(bm + row) * H + f * 8];
    float4 v0 = xp[0], v1 = xp[1];
    float vv[8] = {v0.x, v0.y, v0.z, v0.w, v1.x, v1.y, v1.z, v1.w};
    s16x8 hv;
#pragma unroll
    for (int j = 0; j < 8; ++j) hv[j] = (short)f2bf(aP[j] * vv[j] + bP[j]);
    *(s16x8*)&As[row * LDA + f * 8] = hv;
  }

  s16x8 bh[4][4];
#pragma unroll
  for (int nt = 0; nt < 4; ++nt)
#pragma unroll
    for (int ks = 0; ks < 4; ++ks)
      bh[nt][ks] = *(const s16x8*)&W1h[(size_t)(wn + nt * 16 + l16) * H + ks * 32 + quad * 8];
  __syncthreads();

  f32x4 acc[4][4];
#pragma unroll
  for (int mt = 0; mt < 4; ++mt)
#pragma unroll
    for (int nt = 0; nt < 4; ++nt) acc[mt][nt] = (f32x4){0.f, 0.f, 0.f, 0.f};

#pragma unroll
  for (int ks = 0; ks < 4; ++ks) {
    int kof = ks * 32 + quad * 8;
    s16x8 ah[4];
#pragma unroll
    for (int mt = 0; mt < 4; ++mt) ah[mt] = *(s16x8*)&As[(mt * 16 + l16) * LDA + kof];
#pragma unroll
    for (int mt = 0; mt < 4; ++mt)
#pragma unroll
      for (int nt = 0; nt < 4; ++nt)
        acc[mt][nt] = __builtin_amdgcn_mfma_f32_16x16x32_bf16(ah[mt], bh[nt][ks], acc[mt][nt], 0, 0, 0);
  }

#pragma unroll
  for (int nt = 0; nt < 4; ++nt) {
    int col = wn + nt * 16 + l16;
    float bb = b1[col];
#pragma unroll
    for (int mt = 0; mt < 4; ++mt)
#pragma unroll
      for (int r = 0; r < 4; ++r) {
        int row = bm + mt * 16 + quad * 4 + r;
        float v = acc[mt][nt][r] + bb;
        v = v > 0.f ? v : 0.f;
        t1[(size_t)row * H2 + col] = f2bf(v);
      }
  }
}

// ---------------------------------------------------------------------------
// FFN2: h2 = t1 @ W2 + b2 + BN1(h1) (affine inline); fused BN2 sum/sumsq.
// LDS = A tile only (34 KB).
// ---------------------------------------------------------------------------
__global__ __launch_bounds__(256) void ffn2_mfma(
    const unsigned short* __restrict__ t1, const short* __restrict__ W2h,
    const float* __restrict__ b2, const float* __restrict__ h1,
    const float* __restrict__ sum1, const float* __restrict__ sq1,
    const float* __restrict__ g1, const float* __restrict__ bb1,
    float* __restrict__ h2, float* __restrict__ sum2, float* __restrict__ sq2,
    float invN)
{
  __shared__ __align__(16) short As[64 * LDA2];
  int tid = threadIdx.x;
  int bm = blockIdx.x * 64;
  int wave = tid >> 6, lane = tid & 63;
  int quad = lane >> 4, l16 = lane & 15;
  int wn = wave * 32;

#pragma unroll
  for (int i = 0; i < 8; ++i) {
    int g = i * 256 + tid;
    int row = g >> 5, f = g & 31;
    *(s16x8*)&As[row * LDA2 + f * 8] = *(const s16x8*)&t1[(size_t)(bm + row) * H2 + f * 8];
  }

  s16x8 bh[2][8];
#pragma unroll
  for (int nt = 0; nt < 2; ++nt)
#pragma unroll
    for (int ks = 0; ks < 8; ++ks)
      bh[nt][ks] = *(const s16x8*)&W2h[(size_t)(wn + nt * 16 + l16) * H2 + ks * 32 + quad * 8];
  __syncthreads();

  f32x4 acc[4][2];
#pragma unroll
  for (int mt = 0; mt < 4; ++mt)
#pragma unroll
    for (int nt = 0; nt < 2; ++nt) acc[mt][nt] = (f32x4){0.f, 0.f, 0.f, 0.f};

#pragma unroll
  for (int ks = 0; ks < 8; ++ks) {
    int kof = ks * 32 + quad * 8;
    s16x8 ah[4];
#pragma unroll
    for (int mt = 0; mt < 4; ++mt) ah[mt] = *(s16x8*)&As[(mt * 16 + l16) * LDA2 + kof];
#pragma unroll
    for (int mt = 0; mt < 4; ++mt)
#pragma unroll
      for (int nt = 0; nt < 2; ++nt)
        acc[mt][nt] = __builtin_amdgcn_mfma_f32_16x16x32_bf16(ah[mt], bh[nt][ks], acc[mt][nt], 0, 0, 0);
  }

#pragma unroll
  for (int nt = 0; nt < 2; ++nt) {
    int col = wn + nt * 16 + l16;
    float mu = sum1[col] * invN;
    float var = sq1[col] * invN - mu * mu;
    float rs = rsqrtf(var + EPS);
    float ra = g1[col] * rs;
    float rb = bb1[col] - ra * mu;
    float bb = b2[col];
    float ps = 0.f, pq = 0.f;
#pragma unroll
    for (int mt = 0; mt < 4; ++mt)
#pragma unroll
      for (int r = 0; r < 4; ++r) {
        int row = bm + mt * 16 + quad * 4 + r;
        float rr = ra * h1[(size_t)row * H + col] + rb;
        float v = acc[mt][nt][r] + bb + rr;
        h2[(size_t)row * H + col] = v;
        ps += v; pq += v * v;
      }
    ps += __shfl_xor(ps, 16); ps += __shfl_xor(ps, 32);
    pq += __shfl_xor(pq, 16); pq += __shfl_xor(pq, 32);
    if (quad == 0) {
      atomicAdd(&sum2[col], ps);
      atomicAdd(&sq2[col], pq);
    }
  }
}

// ---------------------------------------------------------------------------
// XCD-grouped edge scatter: 8 groups, each owns N/8 rows, scans all edges,
// writes only its own slab region (keeps dirty lines in one L2).
// ---------------------------------------------------------------------------
__global__ void ebfill(const float* __restrict__ ea,
                       const float* __restrict__ We,
                       const float* __restrict__ be,
                       const int* __restrict__ ei,
                       int* __restrict__ cnt,
                       int2* __restrict__ slabDE, int E, int N)
{
  int grp = blockIdx.x & 7;
  int blk = blockIdx.x >> 3;
  int lo = grp * (N >> 3), hi = lo + (N >> 3);
  int per = E >> 8;                 // edges per window (2048)
  int base = blk * per;
  float4 w0 = *(const float4*)&We[0], w1 = *(const float4*)&We[4];
  float4 w2 = *(const float4*)&We[8], w3 = *(const float4*)&We[12];
  float bias = be[0];
  for (int i = 0; i < per; i += 256) {
    int e = base + i + threadIdx.x;
    if (e >= E) continue;
    int src = ei[e];
    if (src < lo || src >= hi) continue;
    int dst = ei[E + e];
    const float4* p = (const float4*)&ea[(size_t)e * 16];
    float4 a0 = p[0], a1 = p[1], a2 = p[2], a3 = p[3];
    float s = a0.x * w0.x + a0.y * w0.y + a0.z * w0.z + a0.w * w0.w
            + a1.x * w1.x + a1.y * w1.y + a1.z * w1.z + a1.w * w1.w
            + a2.x * w2.x + a2.y * w2.y + a2.z * w2.z + a2.w * w2.w
            + a3.x * w3.x + a3.y * w3.y + a3.z * w3.z + a3.w * w3.w;
    s += bias;
    int pos = atomicAdd(&cnt[src], 1);
    if (pos < SLAB) {
      int2 rec; rec.x = dst; rec.y = __float_as_int(s);
      slabDE[src * SLAB + pos] = rec;
    }
  }
}

// ---------------------------------------------------------------------------
// Slab scores: 2 rows/block, 16 teams of 8 lanes per row, 2 edges per team.
// K gathered as bf16 (4 MB, per-XCD L2 resident); Q fp32.
// ---------------------------------------------------------------------------
__global__ __launch_bounds__(256) void score_slab(
    const float* __restrict__ Q, const unsigned short* __restrict__ Kbf,
    const int* __restrict__ cnt, const int2* __restrict__ slabDE,
    float* __restrict__ sAslab, int N)
{
  int tid = threadIdx.x;
  int team = tid >> 3, sub = tid & 7;
  int local = team & 15;
  int i = blockIdx.x * 2 + (team >> 4);
  int k = cnt[i]; if (k > SLAB) k = SLAB;
  const float4* q4 = (const float4*)(Q + (size_t)i * H);
  float4 qa0 = q4[2 * sub], qa1 = q4[2 * sub + 1];
  float4 qb0 = q4[16 + 2 * sub], qb1 = q4[17 + 2 * sub];
  int base = i * SLAB;

  for (int p = local * 2; p < k; p += 32) {
    int2 de0 = slabDE[base + p];
    bool has1 = (p + 1 < k);
    int2 de1 = has1 ? slabDE[base + p + 1] : de0;
    const s16x8* k0 = (const s16x8*)(Kbf + (size_t)de0.x * H);
    const s16x8* k1 = (const s16x8*)(Kbf + (size_t)de1.x * H);
    s16x8 ka0 = k0[sub], kb0 = k0[8 + sub];
    s16x8 ka1 = k1[sub], kb1 = k1[8 + sub];
    float p0, p1;
    p0 = qa0.x * bf2f((unsigned short)ka0[0]) + qa0.y * bf2f((unsigned short)ka0[1])
       + qa0.z * bf2f((unsigned short)ka0[2]) + qa0.w * bf2f((unsigned short)ka0[3])
       + qa1.x * bf2f((unsigned short)ka0[4]) + qa1.y * bf2f((unsigned short)ka0[5])
       + qa1.z * bf2f((unsigned short)ka0[6]) + qa1.w * bf2f((unsigned short)ka0[7])
       + qb0.x * bf2f((unsigned short)kb0[0]) + qb0.y * bf2f((unsigned short)kb0[1])
       + qb0.z * bf2f((unsigned short)kb0[2]) + qb0.w * bf2f((unsigned short)kb0[3])
       + qb1.x * bf2f((unsigned short)kb0[4]) + qb1.y * bf2f((unsigned short)kb0[5])
       + qb1.z * bf2f((unsigned short)kb0[6]) + qb1.w * bf2f((unsigned short)kb0[7]);
    p1 = qa0.x * bf2f((unsigned short)ka1[0]) + qa0.y * bf2f((unsigned short)ka1[1])
       + qa0.z * bf2f((unsigned short)ka1[2]) + qa0.w * bf2f((unsigned short)ka1[3])
       + qa1.x * bf2f((unsigned short)ka1[4]) + qa1.y * bf2f((unsigned short)ka1[5])
       + qa1.z * bf2f((unsigned short)ka1[6]) + qa1.w * bf2f((unsigned short)ka1[7])
       + qb0.x * bf2f((unsigned short)kb1[0]) + qb0.y * bf2f((unsigned short)kb1[1])
       + qb0.z * bf2f((unsigned short)kb1[2]) + qb0.w * bf2f((unsigned short)kb1[3])
       + qb1.x * bf2f((unsigned short)kb1[4]) + qb1.y * bf2f((unsigned short)kb1[5])
       + qb1.z * bf2f((unsigned short)kb1[6]) + qb1.w * bf2f((unsigned short)kb1[7]);
    p0 += __shfl_xor(p0, 1); p1 += __shfl_xor(p1, 1);
    p0 += __shfl_xor(p0, 2); p1 += __shfl_xor(p1, 2);
    p0 += __shfl_xor(p0, 4); p1 += __shfl_xor(p1, 4);
    if (sub == 0) {
      float s0 = p0 + __int_as_float(de0.y);
      sAslab[base + p] = (s0 >= 0.f) ? s0 : 0.01f * s0;
      if (has1) {
        float s1 = p1 + __int_as_float(de1.y);
        sAslab[base + p + 1] = (s1 >= 0.f) ? s1 : 0.01f * s1;
      }
    }
  }
}

// ---------------------------------------------------------------------------
// Per-row: dedup, sparse softmax vs dense-zero background, P@V (bf16 V),
// fused residual. 32 lanes per row, 8 rows/block.
// ---------------------------------------------------------------------------
__global__ __launch_bounds__(256) void row_slab(
    const float* __restrict__ x, const unsigned short* __restrict__ Vbf,
    const float* __restrict__ SV, const int* __restrict__ cnt,
    const float* __restrict__ sAslab, const int2* __restrict__ slabDE,
    float* __restrict__ h1, int N)
{
  __shared__ float sv[8][SLAB];
  __shared__ int sd[8][SLAB];
  __shared__ unsigned char sown[8][SLAB];
  int team = threadIdx.x >> 5, lane = threadIdx.x & 31;
  int i = blockIdx.x * 8 + team;
  int k = cnt[i]; if (k > SLAB) k = SLAB;
  int base = i * SLAB;

  for (int p = lane; p < k; p += 32) {
    sv[team][p] = sAslab[base + p];
    sd[team][p] = slabDE[base + p].x;
  }
  __syncthreads();

  for (int p = lane; p < k; p += 32) {
    int d = sd[team][p], o = p;
    for (int q = 0; q < p; ++q)
      if (sd[team][q] == d) { o = q; break; }
    sown[team][p] = (unsigned char)o;
  }
  __syncthreads();
  for (int p = lane; p < k; p += 32)
    if (sown[team][p] != (unsigned char)p)
      atomicAdd(&sv[team][sown[team][p]], sv[team][p]);
  __syncthreads();

  float m = 0.f;
  for (int p = lane; p < k; p += 32)
    if (sown[team][p] == (unsigned char)p) m = fmaxf(m, sv[team][p]);
#pragma unroll
  for (int mask = 16; mask; mask >>= 1) m = fmaxf(m, __shfl_xor(m, mask));
  float em = expf(-m);

  float zl = 0.f;
  for (int p = lane; p < k; p += 32) {
    float cf = 0.f;
    if (sown[team][p] == (unsigned char)p) cf = expf(sv[team][p] - m) - em;
    sv[team][p] = cf;
    zl += cf;
  }
#pragma unroll
  for (int mask = 16; mask; mask >>= 1) zl += __shfl_xor(zl, mask);
  float Zi = 1.f / ((float)N * em + zl);
  __syncthreads();

  const ushort4* V4 = (const ushort4*)Vbf;
  float4 s4 = *(const float4*)&SV[lane * 4];
  float ax = em * s4.x, ay = em * s4.y, az = em * s4.z, aw = em * s4.w;
  int c = 0;
  for (; c + 8 <= k; c += 8) {
    float cf[8]; int dd[8]; ushort4 vv[8];
#pragma unroll
    for (int u = 0; u < 8; ++u) { cf[u] = sv[team][c + u]; dd[u] = sd[team][c + u]; }
#pragma unroll
    for (int u = 0; u < 8; ++u) vv[u] = V4[(size_t)dd[u] * 32 + lane];
#pragma unroll
    for (int u = 0; u < 8; ++u) {
      ax += cf[u] * bf2f(vv[u].x);
      ay += cf[u] * bf2f(vv[u].y);
      az += cf[u] * bf2f(vv[u].z);
      aw += cf[u] * bf2f(vv[u].w);
    }
  }
  for (; c < k; ++c) {
    float cf = sv[team][c];
    ushort4 v0 = V4[(size_t)sd[team][c] * 32 + lane];
    ax += cf * bf2f(v0.x); ay += cf * bf2f(v0.y);
    az += cf * bf2f(v0.z); aw += cf * bf2f(v0.w);
  }
  float4 xx = *(const float4*)&x[(size_t)i * H + lane * 4];
  float4 out;
  out.x = xx.x + ax * Zi; out.y = xx.y + ay * Zi;
  out.z = xx.z + az * Zi; out.w = xx.w + aw * Zi;
  *(float4*)&h1[(size_t)i * H + lane * 4] = out;
}

// ---------------------------------------------------------------------------
__global__ __launch_bounds__(128) void colstats(
    const float* __restrict__ X, float* __restrict__ sum,
    float* __restrict__ sumsq, int rowsPerBlock)
{
  int t = threadIdx.x;
  size_t r0 = (size_t)blockIdx.x * rowsPerBlock;
  float s = 0.f, ss = 0.f;
  for (int r = 0; r < rowsPerBlock; ++r) {
    float v = X[(r0 + r) * H + t];
    s += v; ss += v * v;
  }
  atomicAdd(&sum[t], s);
  atomicAdd(&sumsq[t], ss);
}

// BN2 affine computed inline from sums (replaces bn_final dispatch)
__global__ void bn_apply(const float* __restrict__ X,
                         const float* __restrict__ sum2, const float* __restrict__ sq2,
                         const float* __restrict__ g2, const float* __restrict__ bb2,
                         float* __restrict__ Y, size_t n4, float invN)
{
  size_t i = (size_t)blockIdx.x * blockDim.x + threadIdx.x;
  if (i >= n4) return;
  float4 v = ((const float4*)X)[i];
  int c = (int)((i * 4) & (H - 1));
  float4 s = *(const float4*)&sum2[c];
  float4 q = *(const float4*)&sq2[c];
  float4 g = *(const float4*)&g2[c];
  float4 b = *(const float4*)&bb2[c];
  float mu, var, rs, a;
  mu = s.x * invN; var = q.x * invN - mu * mu; rs = rsqrtf(var + EPS);
  a = g.x * rs; v.x = a * v.x + (b.x - a * mu);
  mu = s.y * invN; var = q.y * invN - mu * mu; rs = rsqrtf(var + EPS);
  a = g.y * rs; v.y = a * v.y + (b.y - a * mu);
  mu = s.z * invN; var = q.z * invN - mu * mu; rs = rsqrtf(var + EPS);
  a = g.z * rs; v.z = a * v.z + (b.z - a * mu);
  mu = s.w * invN; var = q.w * invN - mu * mu; rs = rsqrtf(var + EPS);
  a = g.w * rs; v.w = a * v.w + (b.w - a * mu);
  ((float4*)Y)[i] = v;
}

// ---------------------------------------------------------------------------
extern "C" void kernel_launch(void* const* d_in, const int* in_sizes, int n_in,
                              void* d_out, int out_size, void* d_ws, size_t ws_size,
                              hipStream_t stream)
{
  const float* x  = (const float*)d_in[0];
  const int*   ei = (const int*)d_in[1];
  const float* ea = (const float*)d_in[2];
  const float* Wq = (const float*)d_in[3];
  const float* bq = (const float*)d_in[4];
  const float* Wk = (const float*)d_in[5];
  const float* bk = (const float*)d_in[6];
  const float* Wv = (const float*)d_in[7];
  const float* bv = (const float*)d_in[8];
  const float* We = (const float*)d_in[9];
  const float* be = (const float*)d_in[10];
  const float* g1 = (const float*)d_in[11];
  const float* bb1 = (const float*)d_in[12];
  const float* W1 = (const float*)d_in[13];
  const float* b1 = (const float*)d_in[14];
  const float* W2 = (const float*)d_in[15];
  const float* b2 = (const float*)d_in[16];
  const float* g2 = (const float*)d_in[17];
  const float* bb2 = (const float*)d_in[18];

  int N = in_sizes[0] / H;      // 16384
  int E = in_sizes[2] / 16;     // 524288
  size_t NH = (size_t)N * H;
  float invN = 1.0f / (float)N;

  float* Q   = (float*)d_ws;                         // 8 MB
  float* KmSlot = Q + NH;                            // 8 MB (Kbf + later h2)
  float* h1  = KmSlot + NH;                          // 8 MB
  unsigned short* Vbf = (unsigned short*)(h1 + NH);  // 4 MB
  int2*  slabDE = (int2*)(Vbf + NH);                 // 12 MB
  float* sAslab = (float*)(slabDE + (size_t)N * SLAB);  // 6 MB
  int*   cnt    = (int*)(sAslab + (size_t)N * SLAB);
  float* stats  = (float*)(cnt + N);
  float* SV   = stats;            // zeroed
  float* sum1 = stats + H;        // zeroed
  float* sq1  = stats + 2 * H;    // zeroed
  float* sum2 = stats + 3 * H;    // zeroed
  float* sq2  = stats + 4 * H;    // zeroed
  short* wbuf = (short*)(stats + 9 * H + 4);
  short* Wqh = wbuf;
  short* Wql = Wqh + 16384;
  short* Wkh = Wql + 16384;
  short* Wkl = Wkh + 16384;
  short* Wvh = Wkl + 16384;
  short* W1h = Wvh + 16384;
  short* W2h = W1h + 32768;
  unsigned short* Kbf = (unsigned short*)KmSlot;  // 4 MB, dead after score_slab
  unsigned short* t1 = (unsigned short*)Q;        // alias (Q dead after score_slab)
  float* h2 = KmSlot;                             // alias (Kbf dead after score_slab)

  hipMemsetAsync(cnt, 0, (size_t)N * sizeof(int), stream);
  hipMemsetAsync(stats, 0, (size_t)5 * H * sizeof(float), stream);

  wprep<<<dim3(128, 1, 5), 256, 0, stream>>>(Wq, Wk, Wv, W1, W2,
      Wqh, Wql, Wkh, Wkl, Wvh, W1h, W2h);

  qkv_mfma<<<dim3(N / 64), 256, 0, stream>>>(
      x, Wqh, Wql, Wkh, Wkl, Wvh, bq, bk, bv, Q, Kbf, Vbf, SV);

  ebfill<<<dim3(2048), 256, 0, stream>>>(ea, We, be, ei, cnt, slabDE, E, N);
  score_slab<<<dim3(N / 2), 256, 0, stream>>>(Q, Kbf, cnt, slabDE, sAslab, N);
  row_slab<<<dim3(N / 8), 256, 0, stream>>>(x, Vbf, SV, cnt, sAslab, slabDE, h1, N);

  colstats<<<dim3(128), 128, 0, stream>>>(h1, sum1, sq1, N / 128);

  ffn1_mfma<<<dim3(N / 64), 256, 0, stream>>>(h1, W1h, b1, sum1, sq1, g1, bb1, t1, invN);
  ffn2_mfma<<<dim3(N / 64), 256, 0, stream>>>(t1, W2h, b2, h1, sum1, sq1, g1, bb1,
                                              h2, sum2, sq2, invN);

  bn_apply<<<dim3((int)((NH / 4 + 255) / 256)), 256, 0, stream>>>(
      h2, sum2, sq2, g2, bb2, (float*)d_out, NH / 4, invN);
}